// Round 7
// baseline (122.721 us; speedup 1.0000x reference)
//
#include <hip/hip_runtime.h>
#include <math.h>

#define P      512
#define NA     180
#define NB     4
#define FS2    1056    // interleaved pair row: 16 zero + 1024 data + 16 zero floats
#define FOFF2  16
#define GUARD  512     // float guard before/after fil2 for window-staging overreach
#define TS     16      // backprojection pixel tile (16x16 -> 2048 blocks, 8/CU)
#define WSF    56      // window floats per angle (28 positions x 2 batches)
#define ASEG   60      // angles staged per LDS round (3 segments)

#if __has_builtin(__builtin_amdgcn_fractf)
#define FRACT(x) __builtin_amdgcn_fractf(x)
#else
#define FRACT(x) ((x) - floorf(x))
#endif

typedef float f4g __attribute__((ext_vector_type(4), aligned(16)));
typedef float f4l __attribute__((ext_vector_type(4), aligned(8)));

// ---------------------------------------------------------------------------
// K0 (512 x 64): ff[o] = 2*(0.25 + sum_m fodd[m] cos(2pi o(2m+1)/512)) * sinc.
// Direct double cos with exact integer phase mod 512 -- no tables, no LDS.
// ---------------------------------------------------------------------------
__global__ __launch_bounds__(64) void ir_spectrum(float* __restrict__ ffg) {
    const int o = blockIdx.x;
    const int t = threadIdx.x;
    double s = 0.0;
    #pragma unroll
    for (int i = 0; i < 4; ++i) {
        const int m = t + 64 * i;
        const int idx = 2 * m + 1;
        const int n = (idx < 256) ? idx : (512 - idx);
        const double fv = -1.0 / ((M_PI * n) * (M_PI * n));
        const int ph = (o * idx) & 511;
        s += fv * cos((2.0 * M_PI / 512.0) * (double)ph);
    }
    #pragma unroll
    for (int off = 32; off; off >>= 1) s += __shfl_down(s, off, 64);
    if (t == 0) {
        double ff = 0.5 + 2.0 * s;
        if (o > 0) {
            const double freq = (o <= 256) ? (double)o / 512.0 : ((double)o - 512.0) / 512.0;
            const double w = M_PI * freq;   // sinc even; fftfreq sign irrelevant
            ff *= sin(w) / w;
        }
        ffg[o] = (float)ff;
    }
}

// ---------------------------------------------------------------------------
// K1 (512 x 64): hr[o] = (1/512) sum_k ff[k] cos(2pi k o / 512).
// ---------------------------------------------------------------------------
__global__ __launch_bounds__(64) void ir_impulse(const float* __restrict__ ffg,
                                                 float* __restrict__ hr) {
    const int o = blockIdx.x;
    const int t = threadIdx.x;
    double s = 0.0;
    #pragma unroll
    for (int i = 0; i < 8; ++i) {
        const int k = t + 64 * i;
        const int ph = (o * k) & 511;
        s += (double)ffg[k] * cos((2.0 * M_PI / 512.0) * (double)ph);
    }
    #pragma unroll
    for (int off = 32; off; off >>= 1) s += __shfl_down(s, off, 64);
    if (t == 0) hr[o] = (float)(s / 512.0);
}

// ---------------------------------------------------------------------------
// K2: circular conv, filtered[n] = sum_j hr[j] * row[(n-j) mod 512].
// Block = (angle a, batch-pair p). hr read at wave-uniform J -> s_load.
// Rolling register window: A(J+4) == Bv(J), so ONE ds_read_b128 per K-step.
// Output pair-INTERLEAVED: fil2row[16 + 2n + r] = batch(2p+r)[n].
// ---------------------------------------------------------------------------
__global__ __launch_bounds__(256) void ir_filter(const float* __restrict__ sino,
                                                 const float* __restrict__ hr,
                                                 float* __restrict__ fil2) {
    __shared__ float row2[2][2 * P];
    const int a = blockIdx.x;
    const int p = blockIdx.y;
    const int t = threadIdx.x;
    const int r = t >> 7;             // batch within pair
    const int tt = t & 127;           // outputs 4tt..4tt+3
    const int b = 2 * p + r;

    const float* src = sino + ((size_t)b * NA + a) * P;
    const float4 v = *(const float4*)(src + 4 * tt);
    *(float4*)&row2[r][4 * tt] = v;
    *(float4*)&row2[r][4 * tt + P] = v;
    __syncthreads();

    const int base0 = P + 4 * tt;
    float4 A = *(const float4*)&row2[r][base0];    // window floats w[0..3]
    float a0 = 0.f, a1 = 0.f, a2 = 0.f, a3 = 0.f;
    #pragma unroll 4
    for (int J = 0; J < P; J += 4) {
        const float4 Bv = *(const float4*)&row2[r][base0 - J - 4];  // w[-4..-1]
        const float h0 = hr[J], h1 = hr[J + 1], h2v = hr[J + 2], h3 = hr[J + 3];
        a0 = fmaf(h0, A.x, a0); a0 = fmaf(h1, Bv.w, a0); a0 = fmaf(h2v, Bv.z, a0); a0 = fmaf(h3, Bv.y, a0);
        a1 = fmaf(h0, A.y, a1); a1 = fmaf(h1, A.x, a1); a1 = fmaf(h2v, Bv.w, a1); a1 = fmaf(h3, Bv.z, a1);
        a2 = fmaf(h0, A.z, a2); a2 = fmaf(h1, A.y, a2); a2 = fmaf(h2v, A.x, a2); a2 = fmaf(h3, Bv.w, a2);
        a3 = fmaf(h0, A.w, a3); a3 = fmaf(h1, A.z, a3); a3 = fmaf(h2v, A.y, a3); a3 = fmaf(h3, A.x, a3);
        A = Bv;                                    // slide the register window
    }
    float* frow = fil2 + ((size_t)p * NA + a) * FS2;
    const int o0 = FOFF2 + 8 * tt + r;
    frow[o0]     = a0;
    frow[o0 + 2] = a1;
    frow[o0 + 4] = a2;
    frow[o0 + 6] = a3;
    if (t < FOFF2) {                  // zero pads (ws re-poisoned every call)
        frow[t] = 0.f;
        frow[FOFF2 + 2 * P + t] = 0.f;
    }
}

// ---------------------------------------------------------------------------
// K3: backprojection, batch-pair per block, 16x16 tile (2048 blocks -> 8/CU).
// Angle-SEGMENTED windows: 3 rounds of 60 angles in a 13.4 KB LDS buffer ->
// ~16 KB total LDS -> occupancy capped by waves (32/CU), not LDS.
// One 16B LDS read at 2j serves both bilinear taps of BOTH batches.
// ---------------------------------------------------------------------------
__global__ __launch_bounds__(256) void ir_backproject(const float* __restrict__ fil2,
                                                      float* __restrict__ out) {
    __shared__ float4 angc[NA];          // (s, c, qbias = 256 - base, (float)base)
    __shared__ float win[ASEG * WSF];    // 13.4 KB, reused per segment

    const int t = threadIdx.x;
    const int w0 = blockIdx.x * TS, h0 = blockIdx.y * TS;
    const int p = blockIdx.z;            // batch pair

    const int w = w0 + (t & 15);
    const int h = h0 + (t >> 4);

    const int ix = 255 - w;              // reversed x axis
    const int iy = h - 256;
    const int m = (ix * ix + iy * iy) <= 256 * 256;

    float* o0 = out + (((size_t)(2 * p) * P) + h) * P + w;   // batch 2p
    float* o1 = o0 + (size_t)P * P;                          // batch 2p+1

    if (__syncthreads_count(m) == 0) {   // tile fully outside circle
        o0[0] = 0.f;
        o1[0] = 0.f;
        return;
    }

    // Phase A: per-angle constants; even window base from tile-corner bounds
    if (t < NA) {
        const float th = (float)t * (float)(M_PI / (double)(NA - 1));
        const float s = sinf(th), c = cosf(th);           // s >= 0 on [0,pi]
        const float xlo = (float)(240 - w0);              // min x over tile
        const float ylo = (float)(h0 - 256), yhi = (float)(h0 - 241);
        const float pmin = s * xlo + fminf(c * ylo, c * yhi) + 256.0f;
        const int base = ((int)floorf(pmin) - 2) & ~1;    // even, fp-slop safety
        angc[t] = make_float4(s, c, (float)(256 - base), (float)base);
    }
    __syncthreads();

    const float xf = (float)ix;
    const float yf = (float)iy;
    const float* fbase = fil2 + (size_t)p * NA * FS2;
    float acc0 = 0.f, acc1 = 0.f;        // batches 2p, 2p+1

    #pragma unroll
    for (int seg = 0; seg < 3; ++seg) {
        const int A0 = seg * ASEG;

        // Phase B: stage this segment's interleaved windows (16B-aligned)
        for (int idx = t; idx < ASEG * (WSF / 4); idx += 256) {
            const int al = idx / (WSF / 4);
            const int i = idx - al * (WSF / 4);
            const int a = A0 + al;
            const int base = (int)angc[a].w;
            const f4g vv = *(const f4g*)(fbase + a * FS2 + FOFF2 + 2 * base + 4 * i);
            *(f4g*)(win + al * WSF + 4 * i) = vv;
        }
        __syncthreads();

        // Phase C: q = p - base in [~2, 26); j = trunc(q); float4 at 2j =
        // (b0[j], b1[j], b0[j+1], b1[j+1]) -> both taps, both batches, 1 read.
        #pragma unroll 4
        for (int al = 0; al < ASEG; ++al) {
            const float4 ac = angc[A0 + al];
            const float q = fmaf(xf, ac.x, fmaf(yf, ac.y, ac.z));
            const int j = (int)q;
            const float fr = FRACT(q);
            const f4l W = *(const f4l*)(win + al * WSF + 2 * j);
            acc0 = fmaf(1.f - fr, W.x, fmaf(fr, W.z, acc0));
            acc1 = fmaf(1.f - fr, W.y, fmaf(fr, W.w, acc1));
        }
        if (seg < 2) __syncthreads();    // protect win before restage (uniform)
    }

    const float scale = (float)(M_PI / (2.0 * NA));
    o0[0] = m ? acc0 * scale : 0.f;
    o1[0] = m ? acc1 * scale : 0.f;
}

// ---------------------------------------------------------------------------
extern "C" void kernel_launch(void* const* d_in, const int* in_sizes, int n_in,
                              void* d_out, int out_size, void* d_ws, size_t ws_size,
                              hipStream_t stream) {
    const float* sino = (const float*)d_in[0];
    float* out = (float*)d_out;
    float* ws = (float*)d_ws;

    float* ffg  = ws;                      // 512
    float* hr   = ws + 512;                // 512
    float* fil2 = ws + 1024 + GUARD;       // 360 * 1056 = 380160 floats (+guards)

    ir_spectrum<<<P, 64, 0, stream>>>(ffg);
    ir_impulse<<<P, 64, 0, stream>>>(ffg, hr);

    dim3 gridF(NA, NB / 2);
    ir_filter<<<gridF, 256, 0, stream>>>(sino, hr, fil2);

    dim3 gridB(P / TS, P / TS, NB / 2);
    ir_backproject<<<gridB, 256, 0, stream>>>(fil2, out);
}

// Round 8
// 120.496 us; speedup vs baseline: 1.0185x; 1.0185x over previous
//
#include <hip/hip_runtime.h>
#include <math.h>

#define P      512
#define NA     180
#define NB     4
#define FS2    1056    // interleaved pair row: 16 zero + 1024 data + 16 zero floats
#define FOFF2  16
#define GUARD  512     // float guard before/after fil2 for window-staging overreach
#define TS     16      // backprojection pixel tile (16x16 -> 2048 blocks, 8/CU)
#define WSF    56      // window floats per angle (28 positions x 2 batches)
#define ASEG   60      // angles staged per LDS round (3 segments)

#if __has_builtin(__builtin_amdgcn_fractf)
#define FRACT(x) __builtin_amdgcn_fractf(x)
#else
#define FRACT(x) ((x) - floorf(x))
#endif

typedef float f4g __attribute__((ext_vector_type(4), aligned(16)));
typedef float f4l __attribute__((ext_vector_type(4), aligned(8)));

// Per-(tile, angle) even window base. MUST be bit-identical between staging
// (Phase B) and compute (Phase C): one inline function, same float expr.
__device__ __forceinline__ int win_base(float s, float c,
                                        float xlo, float ylo, float yhi) {
    const float pmin = fmaf(s, xlo, fminf(c * ylo, c * yhi) + 256.0f);
    return ((int)floorf(pmin) - 2) & ~1;     // even; -2 = fp-slop safety
}

// ---------------------------------------------------------------------------
// K0 (512 x 64): ff[o] = 2*(0.25 + sum_m fodd[m] cos(2pi o(2m+1)/512)) * sinc.
// Tail: blocks 0..179 also emit the angle sin/cos float2 table.
// ---------------------------------------------------------------------------
__global__ __launch_bounds__(64) void ir_spectrum(float* __restrict__ ffg,
                                                  float2* __restrict__ sct) {
    const int o = blockIdx.x;
    const int t = threadIdx.x;
    double s = 0.0;
    #pragma unroll
    for (int i = 0; i < 4; ++i) {
        const int m = t + 64 * i;
        const int idx = 2 * m + 1;
        const int n = (idx < 256) ? idx : (512 - idx);
        const double fv = -1.0 / ((M_PI * n) * (M_PI * n));
        const int ph = (o * idx) & 511;
        s += fv * cos((2.0 * M_PI / 512.0) * (double)ph);
    }
    #pragma unroll
    for (int off = 32; off; off >>= 1) s += __shfl_down(s, off, 64);
    if (t == 0) {
        double ff = 0.5 + 2.0 * s;
        if (o > 0) {
            const double freq = (o <= 256) ? (double)o / 512.0 : ((double)o - 512.0) / 512.0;
            const double w = M_PI * freq;   // sinc even; fftfreq sign irrelevant
            ff *= sin(w) / w;
        }
        ffg[o] = (float)ff;
        if (o < NA) {
            const float th = (float)o * (float)(M_PI / (double)(NA - 1));
            sct[o] = make_float2(sinf(th), cosf(th));   // s >= 0 on [0,pi]
        }
    }
}

// ---------------------------------------------------------------------------
// K1 (512 x 64): hr[o] = (1/512) sum_k ff[k] cos(2pi k o / 512).
// ---------------------------------------------------------------------------
__global__ __launch_bounds__(64) void ir_impulse(const float* __restrict__ ffg,
                                                 float* __restrict__ hr) {
    const int o = blockIdx.x;
    const int t = threadIdx.x;
    double s = 0.0;
    #pragma unroll
    for (int i = 0; i < 8; ++i) {
        const int k = t + 64 * i;
        const int ph = (o * k) & 511;
        s += (double)ffg[k] * cos((2.0 * M_PI / 512.0) * (double)ph);
    }
    #pragma unroll
    for (int off = 32; off; off >>= 1) s += __shfl_down(s, off, 64);
    if (t == 0) hr[o] = (float)(s / 512.0);
}

// ---------------------------------------------------------------------------
// K2: circular conv, filtered[n] = sum_j hr[j] * row[(n-j) mod 512].
// Block = (angle a, batch-pair p). hr read at wave-uniform J -> s_load.
// Rolling register window: ONE ds_read_b128 per K-step.
// Output pair-INTERLEAVED: fil2row[16 + 2n + r] = batch(2p+r)[n].
// ---------------------------------------------------------------------------
__global__ __launch_bounds__(256) void ir_filter(const float* __restrict__ sino,
                                                 const float* __restrict__ hr,
                                                 float* __restrict__ fil2) {
    __shared__ float row2[2][2 * P];
    const int a = blockIdx.x;
    const int p = blockIdx.y;
    const int t = threadIdx.x;
    const int r = t >> 7;             // batch within pair
    const int tt = t & 127;           // outputs 4tt..4tt+3
    const int b = 2 * p + r;

    const float* src = sino + ((size_t)b * NA + a) * P;
    const float4 v = *(const float4*)(src + 4 * tt);
    *(float4*)&row2[r][4 * tt] = v;
    *(float4*)&row2[r][4 * tt + P] = v;
    __syncthreads();

    const int base0 = P + 4 * tt;
    float4 A = *(const float4*)&row2[r][base0];    // window floats w[0..3]
    float a0 = 0.f, a1 = 0.f, a2 = 0.f, a3 = 0.f;
    #pragma unroll 4
    for (int J = 0; J < P; J += 4) {
        const float4 Bv = *(const float4*)&row2[r][base0 - J - 4];  // w[-4..-1]
        const float h0 = hr[J], h1 = hr[J + 1], h2v = hr[J + 2], h3 = hr[J + 3];
        a0 = fmaf(h0, A.x, a0); a0 = fmaf(h1, Bv.w, a0); a0 = fmaf(h2v, Bv.z, a0); a0 = fmaf(h3, Bv.y, a0);
        a1 = fmaf(h0, A.y, a1); a1 = fmaf(h1, A.x, a1); a1 = fmaf(h2v, Bv.w, a1); a1 = fmaf(h3, Bv.z, a1);
        a2 = fmaf(h0, A.z, a2); a2 = fmaf(h1, A.y, a2); a2 = fmaf(h2v, A.x, a2); a2 = fmaf(h3, Bv.w, a2);
        a3 = fmaf(h0, A.w, a3); a3 = fmaf(h1, A.z, a3); a3 = fmaf(h2v, A.y, a3); a3 = fmaf(h3, A.x, a3);
        A = Bv;                                    // slide the register window
    }
    float* frow = fil2 + ((size_t)p * NA + a) * FS2;
    const int o0 = FOFF2 + 8 * tt + r;
    frow[o0]     = a0;
    frow[o0 + 2] = a1;
    frow[o0 + 4] = a2;
    frow[o0 + 6] = a3;
    if (t < FOFF2) {                  // zero pads (ws re-poisoned every call)
        frow[t] = 0.f;
        frow[FOFF2 + 2 * P + t] = 0.f;
    }
}

// ---------------------------------------------------------------------------
// K3: backprojection, batch-pair per block, 16x16 tile (2048 blocks -> 8/CU).
// Angle-segmented 13.4 KB window buffer; per-angle constants come from a
// global float2 table (wave-uniform -> s_load, SMEM pipe) and the window
// base is recomputed in VALU -- the LDS pipe carries ONLY the win gather
// (one 16B read serves both bilinear taps of both batches).
// ---------------------------------------------------------------------------
__global__ __launch_bounds__(256) void ir_backproject(const float* __restrict__ fil2,
                                                      const float2* __restrict__ sct,
                                                      float* __restrict__ out) {
    __shared__ float win[ASEG * WSF];    // 13.4 KB, reused per segment

    const int t = threadIdx.x;
    const int w0 = blockIdx.x * TS, h0 = blockIdx.y * TS;
    const int p = blockIdx.z;            // batch pair

    const int w = w0 + (t & 15);
    const int h = h0 + (t >> 4);

    const int ix = 255 - w;              // reversed x axis
    const int iy = h - 256;
    const int m = (ix * ix + iy * iy) <= 256 * 256;

    float* o0 = out + (((size_t)(2 * p) * P) + h) * P + w;   // batch 2p
    float* o1 = o0 + (size_t)P * P;                          // batch 2p+1

    if (__syncthreads_count(m) == 0) {   // tile fully outside circle
        o0[0] = 0.f;
        o1[0] = 0.f;
        return;
    }

    // tile-corner bounds for the window base (block-uniform)
    const float xlo = (float)(240 - w0);              // min x over tile
    const float ylo = (float)(h0 - 256), yhi = (float)(h0 - 241);
    const float xf = (float)ix;
    const float yf = (float)iy;
    const float* fbase = fil2 + (size_t)p * NA * FS2;
    float acc0 = 0.f, acc1 = 0.f;        // batches 2p, 2p+1

    #pragma unroll
    for (int seg = 0; seg < 3; ++seg) {
        const int A0 = seg * ASEG;

        // Phase B: stage this segment's interleaved windows (16B-aligned)
        for (int idx = t; idx < ASEG * (WSF / 4); idx += 256) {
            const int al = idx / (WSF / 4);
            const int i = idx - al * (WSF / 4);
            const int a = A0 + al;
            const float2 sc = sct[a];                 // lane-varying -> v-load
            const int base = win_base(sc.x, sc.y, xlo, ylo, yhi);
            const f4g vv = *(const f4g*)(fbase + a * FS2 + FOFF2 + 2 * base + 4 * i);
            *(f4g*)(win + al * WSF + 4 * i) = vv;
        }
        __syncthreads();

        // Phase C: q = p - base in [~2, 26); j = trunc(q); float4 at 2j =
        // (b0[j], b1[j], b0[j+1], b1[j+1]) -> both taps, both batches, 1 read.
        #pragma unroll 4
        for (int al = 0; al < ASEG; ++al) {
            const float2 sc = sct[A0 + al];           // wave-uniform -> s_load
            const float basef = (float)win_base(sc.x, sc.y, xlo, ylo, yhi);
            const float q = fmaf(xf, sc.x, fmaf(yf, sc.y, 256.0f - basef));
            const int j = (int)q;
            const float fr = FRACT(q);
            const f4l W = *(const f4l*)(win + al * WSF + 2 * j);
            acc0 = fmaf(1.f - fr, W.x, fmaf(fr, W.z, acc0));
            acc1 = fmaf(1.f - fr, W.y, fmaf(fr, W.w, acc1));
        }
        if (seg < 2) __syncthreads();    // protect win before restage (uniform)
    }

    const float scale = (float)(M_PI / (2.0 * NA));
    o0[0] = m ? acc0 * scale : 0.f;
    o1[0] = m ? acc1 * scale : 0.f;
}

// ---------------------------------------------------------------------------
extern "C" void kernel_launch(void* const* d_in, const int* in_sizes, int n_in,
                              void* d_out, int out_size, void* d_ws, size_t ws_size,
                              hipStream_t stream) {
    const float* sino = (const float*)d_in[0];
    float* out = (float*)d_out;
    float* ws = (float*)d_ws;

    float* ffg   = ws;                     // 512
    float* hr    = ws + 512;               // 512
    float2* sct  = (float2*)(ws + 1024);   // 180 float2 = 360 floats
    float* fil2  = ws + 1536 + GUARD;      // 360 * 1056 = 380160 floats (+guards)

    ir_spectrum<<<P, 64, 0, stream>>>(ffg, sct);
    ir_impulse<<<P, 64, 0, stream>>>(ffg, hr);

    dim3 gridF(NA, NB / 2);
    ir_filter<<<gridF, 256, 0, stream>>>(sino, hr, fil2);

    dim3 gridB(P / TS, P / TS, NB / 2);
    ir_backproject<<<gridB, 256, 0, stream>>>(fil2, sct, out);
}

// Round 9
// 105.918 us; speedup vs baseline: 1.1586x; 1.1376x over previous
//
#include <hip/hip_runtime.h>
#include <math.h>

#define P      512
#define NA     180
#define NB     4
#define FS2    1056    // interleaved pair row: 16 zero + 1024 data + 16 zero floats
#define FOFF2  16
#define GUARD  512     // float guard before/after fil2 for window-staging overreach
#define TS     16      // backprojection pixel tile (16x16 -> 2048 blocks, 8/CU)
#define WSF    56      // window floats per angle (28 positions x 2 batches)
#define ASEG   60      // angles staged per LDS round (3 segments)
#define NTILES (32 * 32)

#if __has_builtin(__builtin_amdgcn_fractf)
#define FRACT(x) __builtin_amdgcn_fractf(x)
#else
#define FRACT(x) ((x) - floorf(x))
#endif

typedef float f4g __attribute__((ext_vector_type(4), aligned(16)));
typedef float f4l __attribute__((ext_vector_type(4), aligned(8)));

// ---------------------------------------------------------------------------
// K0 (512 x 64): ff[o] = 2*(0.25 + sum_m fodd[m] cos(2pi o(2m+1)/512)) * sinc.
// Tail: blocks 0..179 also emit the angle sin/cos float2 table.
// ---------------------------------------------------------------------------
__global__ __launch_bounds__(64) void ir_spectrum(float* __restrict__ ffg,
                                                  float2* __restrict__ sct) {
    const int o = blockIdx.x;
    const int t = threadIdx.x;
    double s = 0.0;
    #pragma unroll
    for (int i = 0; i < 4; ++i) {
        const int m = t + 64 * i;
        const int idx = 2 * m + 1;
        const int n = (idx < 256) ? idx : (512 - idx);
        const double fv = -1.0 / ((M_PI * n) * (M_PI * n));
        const int ph = (o * idx) & 511;
        s += fv * cos((2.0 * M_PI / 512.0) * (double)ph);
    }
    #pragma unroll
    for (int off = 32; off; off >>= 1) s += __shfl_down(s, off, 64);
    if (t == 0) {
        double ff = 0.5 + 2.0 * s;
        if (o > 0) {
            const double freq = (o <= 256) ? (double)o / 512.0 : ((double)o - 512.0) / 512.0;
            const double w = M_PI * freq;   // sinc even; fftfreq sign irrelevant
            ff *= sin(w) / w;
        }
        ffg[o] = (float)ff;
        if (o < NA) {
            const float th = (float)o * (float)(M_PI / (double)(NA - 1));
            sct[o] = make_float2(sinf(th), cosf(th));   // s >= 0 on [0,pi]
        }
    }
}

// ---------------------------------------------------------------------------
// K1 (512 x 64): hr[o] = (1/512) sum_k ff[k] cos(2pi k o / 512).
// ---------------------------------------------------------------------------
__global__ __launch_bounds__(64) void ir_impulse(const float* __restrict__ ffg,
                                                 float* __restrict__ hr) {
    const int o = blockIdx.x;
    const int t = threadIdx.x;
    double s = 0.0;
    #pragma unroll
    for (int i = 0; i < 8; ++i) {
        const int k = t + 64 * i;
        const int ph = (o * k) & 511;
        s += (double)ffg[k] * cos((2.0 * M_PI / 512.0) * (double)ph);
    }
    #pragma unroll
    for (int off = 32; off; off >>= 1) s += __shfl_down(s, off, 64);
    if (t == 0) hr[o] = (float)(s / 512.0);
}

// ---------------------------------------------------------------------------
// K2: circular conv (blocks p<2) + window-base table build (blocks p==2).
// Conv: filtered[n] = sum_j hr[j] * row[(n-j) mod 512], hr via s_load,
// rolling register window -> ONE ds_read_b128 per K-step, pair-interleaved
// output. Table: qbt[tile*180+a] = 256 - base(tile, a); SINGLE source of
// truth for staging & compute in K3 (no recompute divergence possible).
// ---------------------------------------------------------------------------
__global__ __launch_bounds__(256) void ir_filter(const float* __restrict__ sino,
                                                 const float* __restrict__ hr,
                                                 float* __restrict__ fil2,
                                                 const float2* __restrict__ sct,
                                                 float* __restrict__ qbt) {
    __shared__ float row2[2][2 * P];
    const int a = blockIdx.x;
    const int p = blockIdx.y;
    const int t = threadIdx.x;

    if (p == 2) {                     // window-base table for angle a
        const float2 sc = sct[a];
        #pragma unroll
        for (int i = 0; i < 4; ++i) {
            const int tile = t + 256 * i;          // by*32+bx
            const int bx = tile & 31, by = tile >> 5;
            const float xlo = (float)(240 - 16 * bx);   // min x over tile
            const float ylo = (float)(16 * by - 256);
            const float yhi = (float)(16 * by - 241);
            const float pmin = fmaf(sc.x, xlo, fminf(sc.y * ylo, sc.y * yhi) + 256.0f);
            const int base = ((int)floorf(pmin) - 2) & ~1;  // even, fp-slop safety
            qbt[tile * NA + a] = (float)(256 - base);
        }
        return;
    }

    const int r = t >> 7;             // batch within pair
    const int tt = t & 127;           // outputs 4tt..4tt+3
    const int b = 2 * p + r;

    const float* src = sino + ((size_t)b * NA + a) * P;
    const float4 v = *(const float4*)(src + 4 * tt);
    *(float4*)&row2[r][4 * tt] = v;
    *(float4*)&row2[r][4 * tt + P] = v;
    __syncthreads();

    const int base0 = P + 4 * tt;
    float4 A = *(const float4*)&row2[r][base0];    // window floats w[0..3]
    float a0 = 0.f, a1 = 0.f, a2 = 0.f, a3 = 0.f;
    #pragma unroll 4
    for (int J = 0; J < P; J += 4) {
        const float4 Bv = *(const float4*)&row2[r][base0 - J - 4];  // w[-4..-1]
        const float h0 = hr[J], h1 = hr[J + 1], h2v = hr[J + 2], h3 = hr[J + 3];
        a0 = fmaf(h0, A.x, a0); a0 = fmaf(h1, Bv.w, a0); a0 = fmaf(h2v, Bv.z, a0); a0 = fmaf(h3, Bv.y, a0);
        a1 = fmaf(h0, A.y, a1); a1 = fmaf(h1, A.x, a1); a1 = fmaf(h2v, Bv.w, a1); a1 = fmaf(h3, Bv.z, a1);
        a2 = fmaf(h0, A.z, a2); a2 = fmaf(h1, A.y, a2); a2 = fmaf(h2v, A.x, a2); a2 = fmaf(h3, Bv.w, a2);
        a3 = fmaf(h0, A.w, a3); a3 = fmaf(h1, A.z, a3); a3 = fmaf(h2v, A.y, a3); a3 = fmaf(h3, A.x, a3);
        A = Bv;                                    // slide the register window
    }
    float* frow = fil2 + ((size_t)p * NA + a) * FS2;
    const int o0 = FOFF2 + 8 * tt + r;
    frow[o0]     = a0;
    frow[o0 + 2] = a1;
    frow[o0 + 4] = a2;
    frow[o0 + 6] = a3;
    if (t < FOFF2) {                  // zero pads (ws re-poisoned every call)
        frow[t] = 0.f;
        frow[FOFF2 + 2 * P + t] = 0.f;
    }
}

// ---------------------------------------------------------------------------
// K3: backprojection, batch-pair per block, 16x16 tile (2048 blocks, 8/CU).
// Angle-segmented 13.4 KB window buffer. Per-angle constants (s, c, qb) are
// wave-uniform s_loads from global tables -- the LDS pipe carries ONLY the
// win gather (one 16B read serves both bilinear taps of both batches), and
// the VALU inner loop is ~10 instructions.
// ---------------------------------------------------------------------------
__global__ __launch_bounds__(256) void ir_backproject(const float* __restrict__ fil2,
                                                      const float2* __restrict__ sct,
                                                      const float* __restrict__ qbt,
                                                      float* __restrict__ out) {
    __shared__ float win[ASEG * WSF];    // 13.4 KB, reused per segment

    const int t = threadIdx.x;
    const int w0 = blockIdx.x * TS, h0 = blockIdx.y * TS;
    const int p = blockIdx.z;            // batch pair
    const float* qrow = qbt + (blockIdx.y * 32 + blockIdx.x) * NA;  // this tile's bases

    const int w = w0 + (t & 15);
    const int h = h0 + (t >> 4);

    const int ix = 255 - w;              // reversed x axis
    const int iy = h - 256;
    const int m = (ix * ix + iy * iy) <= 256 * 256;

    float* o0 = out + (((size_t)(2 * p) * P) + h) * P + w;   // batch 2p
    float* o1 = o0 + (size_t)P * P;                          // batch 2p+1

    if (__syncthreads_count(m) == 0) {   // tile fully outside circle
        o0[0] = 0.f;
        o1[0] = 0.f;
        return;
    }

    const float xf = (float)ix;
    const float yf = (float)iy;
    const float* fbase = fil2 + (size_t)p * NA * FS2;
    float acc0 = 0.f, acc1 = 0.f;        // batches 2p, 2p+1

    #pragma unroll
    for (int seg = 0; seg < 3; ++seg) {
        const int A0 = seg * ASEG;

        // Phase B: stage this segment's interleaved windows (16B-aligned)
        for (int idx = t; idx < ASEG * (WSF / 4); idx += 256) {
            const int al = idx / (WSF / 4);
            const int i = idx - al * (WSF / 4);
            const int a = A0 + al;
            const int base = 256 - (int)qrow[a];          // lane-varying -> v-load
            const f4g vv = *(const f4g*)(fbase + a * FS2 + FOFF2 + 2 * base + 4 * i);
            *(f4g*)(win + al * WSF + 4 * i) = vv;
        }
        __syncthreads();

        // Phase C: q = p - base in [~2, 26); j = trunc(q); float4 at 2j =
        // (b0[j], b1[j], b0[j+1], b1[j+1]) -> both taps, both batches, 1 read.
        #pragma unroll 4
        for (int al = 0; al < ASEG; ++al) {
            const float2 sc = sct[A0 + al];               // wave-uniform -> s_load
            const float qb = qrow[A0 + al];               // wave-uniform -> s_load
            const float q = fmaf(xf, sc.x, fmaf(yf, sc.y, qb));
            const int j = (int)q;
            const float fr = FRACT(q);
            const f4l W = *(const f4l*)(win + al * WSF + 2 * j);
            acc0 = fmaf(1.f - fr, W.x, fmaf(fr, W.z, acc0));
            acc1 = fmaf(1.f - fr, W.y, fmaf(fr, W.w, acc1));
        }
        if (seg < 2) __syncthreads();    // protect win before restage (uniform)
    }

    const float scale = (float)(M_PI / (2.0 * NA));
    o0[0] = m ? acc0 * scale : 0.f;
    o1[0] = m ? acc1 * scale : 0.f;
}

// ---------------------------------------------------------------------------
extern "C" void kernel_launch(void* const* d_in, const int* in_sizes, int n_in,
                              void* d_out, int out_size, void* d_ws, size_t ws_size,
                              hipStream_t stream) {
    const float* sino = (const float*)d_in[0];
    float* out = (float*)d_out;
    float* ws = (float*)d_ws;

    float* ffg   = ws;                       // 512
    float* hr    = ws + 512;                 // 512
    float2* sct  = (float2*)(ws + 1024);     // 180 float2 -> 512 slot
    float* qbt   = ws + 1536;                // 1024 tiles * 180 = 184320 floats
    float* fil2  = ws + 1536 + NTILES * NA + GUARD;   // 360*1056 floats (+guards)

    ir_spectrum<<<P, 64, 0, stream>>>(ffg, sct);
    ir_impulse<<<P, 64, 0, stream>>>(ffg, hr);

    dim3 gridF(NA, 3);                       // y=0,1: conv pairs; y=2: qbt build
    ir_filter<<<gridF, 256, 0, stream>>>(sino, hr, fil2, sct, qbt);

    dim3 gridB(P / TS, P / TS, NB / 2);
    ir_backproject<<<gridB, 256, 0, stream>>>(fil2, sct, qbt, out);
}